// Round 5
// baseline (209.469 us; speedup 1.0000x reference)
//
#include <hip/hip_runtime.h>

#define B_ 64
#define T_ 512
#define D_ 768
#define K_ 21
#define NCHUNK 32    // chunks over t=1..511
#define CLEN 16
#define GSTRIDE 448  // padded 21*21
#define LOG21 3.0445224377234229965f
#define WSTRIDE 776  // W LDS row stride (halves), mult of 8

using f16x8 = __attribute__((ext_vector_type(8))) _Float16;
using h16x4 = __attribute__((ext_vector_type(4))) _Float16;
using f32x4 = __attribute__((ext_vector_type(4))) float;

// ---------------- Kernel 1: logits = A@W^T + b, barrier-free register-A MFMA --
// r4 evidence: the old LDS-staged GEMM ran ~55-60us (vs 16us HBM floor) — the
// per-tile __syncthreads + vmcnt(0) drain coupled all waves into synchronized
// load bursts (~2 TB/s effective). Each wave's A-fragments come only from its
// own 16 rows, so A skips LDS entirely: straight global->reg->f16 fragments,
// 1-tile register prefetch, waves free-run. Only one barrier (W staging).
// LDS 32.6KB; launch_bounds(256,4) caps VGPR at 128 (est ~100).
__global__ __launch_bounds__(256, 4) void proj_kernel(
    const float* __restrict__ A,
    const float* __restrict__ W,
    const float* __restrict__ bias,
    float* __restrict__ out)            // d_out: [0]=loss, [1..]=logits
{
    __shared__ _Float16 Wh[K_ * WSTRIDE];     // 32592 B
    const int tid  = threadIdx.x;
    const int lane = tid & 63;
    const int w    = tid >> 6;
    const int m    = lane & 15;
    const int quad = lane >> 4;
    const int gw   = blockIdx.x * 4 + w;      // global wave id, 0..2047
    const float* Arow = A + ((size_t)gw * 16 + m) * D_;   // this lane's A row

    // prefetch kt=0 A fragments (8 float4/lane) — in flight during W staging
    float4 pf[8];
    #pragma unroll
    for (int j = 0; j < 8; ++j) {
        const int s = j >> 1;
        const int off = s * 32 + quad * 8 + (j & 1) * 4;
        pf[j] = *(const float4*)(Arow + off);
    }

    // stage W f32->f16 (coalesced, all 256 threads)
    {
        const float4* Wg = (const float4*)W;
        for (int i = tid; i < K_ * D_ / 4; i += 256) {
            const float4 v = Wg[i];
            const int fi = i * 4;
            const int r = fi / D_;
            const int c = fi - r * D_;
            h16x4 h;
            h[0] = (_Float16)v.x; h[1] = (_Float16)v.y;
            h[2] = (_Float16)v.z; h[3] = (_Float16)v.w;
            *(h16x4*)(&Wh[r * WSTRIDE + c]) = h;
        }
    }
    __syncthreads();                          // the only block barrier

    f32x4 acc0 = {0.f, 0.f, 0.f, 0.f};
    f32x4 acc1 = {0.f, 0.f, 0.f, 0.f};
    const int n1 = (16 + m < K_) ? 16 + m : K_ - 1;

    for (int kt = 0; kt < 6; ++kt) {
        // convert current tile's staged f32 -> f16 A-fragments (waits own vmcnt)
        f16x8 af[4];
        #pragma unroll
        for (int s = 0; s < 4; ++s) {
            const float4 v0 = pf[2 * s], v1 = pf[2 * s + 1];
            f16x8 a;
            a[0] = (_Float16)v0.x; a[1] = (_Float16)v0.y;
            a[2] = (_Float16)v0.z; a[3] = (_Float16)v0.w;
            a[4] = (_Float16)v1.x; a[5] = (_Float16)v1.y;
            a[6] = (_Float16)v1.z; a[7] = (_Float16)v1.w;
            af[s] = a;
        }
        // issue next tile's loads — overlap the MFMA below
        if (kt < 5) {
            const float* An = Arow + (kt + 1) * 128;
            #pragma unroll
            for (int j = 0; j < 8; ++j) {
                const int s = j >> 1;
                const int off = s * 32 + quad * 8 + (j & 1) * 4;
                pf[j] = *(const float4*)(An + off);
            }
        }
        #pragma unroll
        for (int s = 0; s < 4; ++s) {
            const f16x8 bf = *(const f16x8*)(&Wh[m  * WSTRIDE + kt * 128 + s * 32 + quad * 8]);
            const f16x8 cf = *(const f16x8*)(&Wh[n1 * WSTRIDE + kt * 128 + s * 32 + quad * 8]);
            acc0 = __builtin_amdgcn_mfma_f32_16x16x32_f16(af[s], bf, acc0, 0, 0, 0);
            acc1 = __builtin_amdgcn_mfma_f32_16x16x32_f16(af[s], cf, acc1, 0, 0, 0);
        }
    }

    // epilogue (C layout verified: col=lane&15, row=quad*4+reg)
    const size_t rbase = (size_t)gw * 16 + quad * 4;
    {
        const float bb = bias[m];
        float* o = out + 1 + rbase * K_ + m;
        #pragma unroll
        for (int r = 0; r < 4; ++r) o[(size_t)r * K_] = acc0[r] + bb;
    }
    const int col2 = 16 + m;
    if (col2 < K_) {
        const float bb = bias[col2];
        float* o = out + 1 + rbase * K_ + col2;
        #pragma unroll
        for (int r = 0; r < 4; ++r) o[(size_t)r * K_] = acc1[r] + bb;
    }
}

// ---------------- Kernel 2a: per-(batch,chunk) transfer-matrix product --------
// One wave per task, __launch_bounds__(64,1) gives the full VGPR budget so
// ETc[147] stays in registers (proven config). Arms kernel 2b's counter.
__global__ __launch_bounds__(64, 1) void chunk_kernel(
    const float* __restrict__ outF,
    const int*   __restrict__ mask,
    const float* __restrict__ trans,
    float* __restrict__ G,
    float* __restrict__ SC,
    int*   __restrict__ cnt)
{
    __shared__ float M0[441], M1[441];
    __shared__ float sET[441];
    __shared__ float em[CLEN * K_];
    __shared__ float smx[CLEN];
    __shared__ int   smask[CLEN];

    const int c = blockIdx.x;
    const int b = blockIdx.y;
    const int lane = threadIdx.x;
    if (c == 0 && b == 0 && lane == 0) *cnt = 0;   // arm scan_fin's counter
    const int t0 = c * CLEN + 1;
    const int nst = min(CLEN, T_ - t0);     // 16, except 15 for last chunk
    const int i_ = lane / 3;
    const int jg = lane - i_ * 3;
    const bool act = lane < 63;

    const float* lg = outF + 1 + (size_t)b * T_ * K_;
    for (int idx = lane; idx < nst * K_; idx += 64) em[idx] = lg[t0 * K_ + idx];
    if (lane < nst) smask[lane] = mask[b * T_ + t0 + lane];
    for (int idx = lane; idx < 441; idx += 64) {
        M0[idx] = (idx % 22 == 0) ? 1.0f : 0.0f;
        sET[idx] = __expf(trans[idx]);
    }
    __syncthreads();

    if (lane < nst) {
        float mx = -1e30f;
        for (int j = 0; j < K_; ++j) mx = fmaxf(mx, em[lane * K_ + j]);
        smx[lane] = mx;
    }
    __syncthreads();
    for (int idx = lane; idx < nst * K_; idx += 64)
        em[idx] = __expf(em[idx] - smx[idx / K_]) * (1.0f / 21.0f);

    float ETc[K_ * 7];
    if (act) {
        #pragma unroll
        for (int mm = 0; mm < K_; ++mm) {
            #pragma unroll
            for (int q = 0; q < 7; ++q)
                ETc[mm * 7 + q] = sET[mm * K_ + jg * 7 + q];
        }
    }
    __syncthreads();

    int cur = 0;
    for (int s = 0; s < nst; ++s) {
        if (smask[s] != 0) {                 // wave-uniform
            const float* Mr = cur ? M1 : M0;
            float*       Mw = cur ? M0 : M1;
            float facc[7] = {0.f,0.f,0.f,0.f,0.f,0.f,0.f};
            if (act) {
                #pragma unroll
                for (int mm = 0; mm < K_; ++mm) {
                    const float lm = Mr[i_ * K_ + mm];
                    #pragma unroll
                    for (int q = 0; q < 7; ++q)
                        facc[q] = fmaf(lm, ETc[mm * 7 + q], facc[q]);
                }
            }
            __syncthreads();
            if (act) {
                #pragma unroll
                for (int q = 0; q < 7; ++q)
                    Mw[i_ * K_ + jg * 7 + q] = facc[q] * em[s * K_ + jg * 7 + q];
            }
            __syncthreads();
            cur ^= 1;
        }
    }

    float* Gc = G + (size_t)(b * NCHUNK + c) * GSTRIDE;
    const float* Mf = cur ? M1 : M0;
    for (int idx = lane; idx < 441; idx += 64) Gc[idx] = Mf[idx];
    if (lane == 0) {
        float sc = 0.0f;
        for (int s = 0; s < nst; ++s)
            if (smask[s] != 0) sc += smx[s] + LOG21;
        SC[b * NCHUNK + c] = sc;
    }
}

// ---------------- Kernel 2b: scan + gold score + fused final reduction --------
// 4 waves stage G (56KB) + masks; wave 0 runs the 32-step scan with shuffle-
// broadcast v and lane0-renorm; waves 1-3 compute the gold-path score. Last
// block to arrive (device-scope counter, armed by chunk_kernel) reduces ll/ms
// and writes the loss — no separate fin launch.
__global__ __launch_bounds__(256) void scan_fin_kernel(
    const float* __restrict__ outF,
    const int*   __restrict__ tags,
    const int*   __restrict__ mask,
    const float* __restrict__ trans,
    const float* __restrict__ startT,
    const float* __restrict__ endT,
    const float* __restrict__ G,
    const float* __restrict__ SC,
    float* __restrict__ ll,
    float* __restrict__ msum,
    int*   __restrict__ cnt,
    float* __restrict__ outW)
{
    __shared__ float sG[NCHUNK * GSTRIDE];   // 57344 B
    __shared__ float sm[T_];
    __shared__ int   st[T_];
    __shared__ float part[8];
    __shared__ int   lastF;
    const int tid = threadIdx.x;
    const int lane = tid & 63;
    const int w = tid >> 6;
    const int b = blockIdx.x;
    const float* lg = outF + 1 + (size_t)b * T_ * K_;

    {
        const float4* Gf4 = (const float4*)(G + (size_t)b * NCHUNK * GSTRIDE);
        float4* dst = (float4*)sG;
        for (int i = tid; i < NCHUNK * GSTRIDE / 4; i += 256) dst[i] = Gf4[i];
    }
    for (int t = tid; t < T_; t += 256) {
        sm[t] = (float)mask[b * T_ + t];
        st[t] = tags[b * T_ + t];
    }
    __syncthreads();

    float logZ = 0.0f;
    if (w == 0) {
        const float scv = (lane < NCHUNK) ? SC[b * NCHUNK + lane] : 0.0f;
        const int jc = min(lane, K_ - 1);
        float v = (lane < K_) ? __expf(startT[lane] + lg[lane]) : 0.0f;
        float C = 0.0f;
        for (int c = 0; c < NCHUNK; ++c) {
            const float* Gc = sG + c * GSTRIDE;
            float a0 = 0.f, a1 = 0.f, a2 = 0.f;
            #pragma unroll
            for (int i = 0; i < K_; i += 3) {
                a0 = fmaf(__shfl(v, i,     64), Gc[i * K_ + jc],       a0);
                a1 = fmaf(__shfl(v, i + 1, 64), Gc[(i + 1) * K_ + jc], a1);
                a2 = fmaf(__shfl(v, i + 2, 64), Gc[(i + 2) * K_ + jc], a2);
            }
            const float s = a0 + a1 + a2;
            const float s0 = __shfl(s, 0, 64);     // >0 always (all-positive G)
            v = s / s0;
            C += __logf(s0) + __shfl(scv, c, 64);
        }
        float term = (lane < K_) ? v * __expf(endT[lane]) : 0.0f;
        #pragma unroll
        for (int off = 16; off >= 1; off >>= 1) term += __shfl_xor(term, off, 64);
        term += __shfl_xor(term, 32, 64);
        logZ = C + __logf(term);
    } else {
        float sc = 0.0f, ms = 0.0f;
        for (int t = tid - 64; t < T_; t += 192) {
            const float mt = sm[t];
            ms += mt;
            if (t < T_ - 1) {
                const int ct = st[t], nt2 = st[t + 1];
                sc += trans[ct * K_ + nt2] * sm[t + 1] + lg[t * K_ + ct] * mt;
            }
        }
        #pragma unroll
        for (int off = 32; off >= 1; off >>= 1) {
            sc += __shfl_xor(sc, off, 64);
            ms += __shfl_xor(ms, off, 64);
        }
        if (lane == 0) { part[w] = sc; part[4 + w] = ms; }
    }
    __syncthreads();

    if (tid == 0) {
        float sc = part[1] + part[2] + part[3];
        float ms = part[5] + part[6] + part[7];
        const int lastIdx = (int)ms - 1;
        const int lastTag = st[lastIdx];
        sc += startT[st[0]] + endT[lastTag] + lg[(T_ - 1) * K_ + lastTag] * sm[T_ - 1];
        ll[b]   = sc - logZ;
        msum[b] = ms;
        __threadfence();                          // release our ll/ms
        lastF = (atomicAdd(cnt, 1) == B_ - 1) ? 1 : 0;
    }
    __syncthreads();

    if (lastF != 0 && w == 0) {
        __threadfence();                          // acquire others' ll/ms
        float l  = ll[lane];
        float mm = msum[lane];
        #pragma unroll
        for (int off = 32; off >= 1; off >>= 1) {
            l  += __shfl_xor(l,  off, 64);
            mm += __shfl_xor(mm, off, 64);
        }
        if (lane == 0) outW[0] = -l / mm;
    }
}

// ---------------- Kernel 3 (fallback only): loss = -sum(ll)/sum(mask) ---------
__global__ __launch_bounds__(64) void fin_kernel(
    const float* __restrict__ ll, const float* __restrict__ msum,
    float* __restrict__ outF)
{
    const int lane = threadIdx.x;
    float l = ll[lane];
    float m = msum[lane];
    #pragma unroll
    for (int off = 32; off >= 1; off >>= 1) {
        l += __shfl_xor(l, off, 64);
        m += __shfl_xor(m, off, 64);
    }
    if (lane == 0) outF[0] = -l / m;
}

// ---------------- Fallback (ws too small): sequential CRF ----------------------
__global__ __launch_bounds__(64) void crf_kernel(
    const float* __restrict__ outF,
    const int*   __restrict__ tags,
    const int*   __restrict__ mask,
    const float* __restrict__ trans,
    const float* __restrict__ startT,
    const float* __restrict__ endT,
    float* __restrict__ ws)
{
    __shared__ float se[T_ * K_];
    __shared__ float sm[T_];
    __shared__ int   st[T_];
    const int b = blockIdx.x;
    const int lane = threadIdx.x;

    const float* lg = outF + 1 + (size_t)b * T_ * K_;
    for (int i = lane; i < T_ * K_; i += 64) se[i] = lg[i];
    for (int t = lane; t < T_; t += 64) {
        sm[t] = (float)mask[b * T_ + t];
        st[t] = tags[b * T_ + t];
    }
    __syncthreads();

    const int jc = lane < K_ ? lane : K_ - 1;
    float ET[K_];
    #pragma unroll
    for (int i = 0; i < K_; ++i) ET[i] = __expf(trans[i * K_ + jc]);

    float a0   = startT[jc] + se[jc];
    float r0   = __shfl(a0, 0, 64);
    float aRel = a0 - r0;
    float C    = r0;

    for (int t = 1; t < T_; ++t) {
        if (sm[t] != 0.0f) {
            float e = __expf(aRel);
            float s = 0.0f;
            #pragma unroll
            for (int i = 0; i < K_; ++i)
                s = fmaf(__shfl(e, i, 64), ET[i], s);
            float raw = __logf(s) + se[t * K_ + jc];
            float rr  = __shfl(raw, 0, 64);
            aRel = raw - rr;
            C   += rr;
        }
    }

    float contrib = (lane < K_) ? __expf(aRel + endT[jc]) : 0.0f;
    #pragma unroll
    for (int off = 32; off >= 1; off >>= 1) contrib += __shfl_xor(contrib, off, 64);
    const float logZ = C + __logf(contrib);

    float sc = 0.0f, ms = 0.0f;
    for (int t = lane; t < T_; t += 64) {
        const float mt = sm[t];
        ms += mt;
        if (t < T_ - 1) {
            const int ct = st[t], nt2 = st[t + 1];
            sc += trans[ct * K_ + nt2] * sm[t + 1] + se[t * K_ + ct] * mt;
        }
    }
    #pragma unroll
    for (int off = 32; off >= 1; off >>= 1) {
        sc += __shfl_xor(sc, off, 64);
        ms += __shfl_xor(ms, off, 64);
    }
    if (lane == 0) {
        const int lastIdx = (int)ms - 1;
        const int lastTag = st[lastIdx];
        sc += startT[st[0]] + endT[lastTag] + se[(T_ - 1) * K_ + lastTag] * sm[T_ - 1];
        ws[b]      = sc - logZ;
        ws[B_ + b] = ms;
    }
}

extern "C" void kernel_launch(void* const* d_in, const int* in_sizes, int n_in,
                              void* d_out, int out_size, void* d_ws, size_t ws_size,
                              hipStream_t stream) {
    const float* A     = (const float*)d_in[0];   // vectors [64,512,768] f32
    const int*   tags  = (const int*)  d_in[1];   // targets [64,512] i32
    const int*   mask  = (const int*)  d_in[2];   // mask    [64,512] i32
    const float* W     = (const float*)d_in[3];   // W [21,768] f32
    const float* bias  = (const float*)d_in[4];   // b [21]
    const float* trans = (const float*)d_in[5];   // transitions [21,21]
    const float* stT   = (const float*)d_in[6];   // start_trans [21]
    const float* enT   = (const float*)d_in[7];   // end_trans [21]
    float* outF = (float*)d_out;
    float* ws   = (float*)d_ws;

    // ws layout (floats): G[64*32*448] | SC[64*32] | ll[64] | ms[64] | cnt(int)
    const size_t gFloats = (size_t)B_ * NCHUNK * GSTRIDE;
    const size_t scOff   = gFloats;
    const size_t llOff   = scOff + (size_t)B_ * NCHUNK;
    const size_t msOff   = llOff + B_;
    const size_t cntOff  = msOff + B_;
    const size_t needBytes = cntOff * sizeof(float) + sizeof(int);

    proj_kernel<<<512, 256, 0, stream>>>(A, W, bias, outF);

    if (ws_size >= needBytes) {
        float* G   = ws;
        float* SC  = ws + scOff;
        float* llp = ws + llOff;
        float* msv = ws + msOff;
        int*   cnt = (int*)(ws + cntOff);
        chunk_kernel<<<dim3(NCHUNK, B_), 64, 0, stream>>>(outF, mask, trans, G, SC, cnt);
        scan_fin_kernel<<<B_, 256, 0, stream>>>(outF, tags, mask, trans, stT, enT, G, SC, llp, msv, cnt, outF);
    } else {
        crf_kernel<<<B_, 64, 0, stream>>>(outF, tags, mask, trans, stT, enT, ws);
        fin_kernel<<<1, 64, 0, stream>>>(ws, ws + B_, outF);
    }
}

// Round 6
// 205.666 us; speedup vs baseline: 1.0185x; 1.0185x over previous
//
#include <hip/hip_runtime.h>

#define B_ 64
#define T_ 512
#define D_ 768
#define K_ 21
#define NCHUNK 32    // chunks over t=1..511
#define CLEN 16
#define GSTRIDE 448  // padded 21*21
#define LOG21 3.0445224377234229965f
#define WSTRIDE 776  // W LDS row stride (halves), mult of 8

using f16x8 = __attribute__((ext_vector_type(8))) _Float16;
using h16x4 = __attribute__((ext_vector_type(4))) _Float16;
using f32x4 = __attribute__((ext_vector_type(4))) float;

// ---------------- Kernel 1: logits = A@W^T + b, K-split-4 max-MLP MFMA --------
// r5 evidence: LDS-staged and register-A GEMMs both ran ~58us (1.7 TB/s eff) —
// latency/MLP-bound: 8 KB in flight per wave, 8 waves/CU. This version floods
// the memory system: 2048 blocks (16 rows each), wave w owns K-quarter w and
// issues its ENTIRE 12-KB A slice upfront (no drain-reload pipeline); 16
// waves/CU (4 blocks x 4 waves, LDS 32.6KB), ~192 KB/CU in flight. Partial
// accumulators summed via an 8-KB LDS overlay on the dead W buffer.
__global__ __launch_bounds__(256, 4) void proj_kernel(
    const float* __restrict__ A,
    const float* __restrict__ W,
    const float* __restrict__ bias,
    float* __restrict__ out)            // d_out: [0]=loss, [1..]=logits
{
    __shared__ _Float16 Wh[K_ * WSTRIDE];     // 32592 B; first 8KB reused as red[]
    const int tid  = threadIdx.x;
    const int lane = tid & 63;
    const int w    = tid >> 6;                // K-quarter 0..3
    const int m    = lane & 15;
    const int quad = lane >> 4;
    const int gw   = blockIdx.x;              // 16-row group, 0..2047
    const float* Arow = A + ((size_t)gw * 16 + m) * D_ + w * 192;

    // issue the wave's ENTIRE A slice upfront: 12 x dwordx4 = 12 KB in flight
    float4 pf[12];
    #pragma unroll
    for (int j = 0; j < 12; ++j) {
        const int s = j >> 1;
        const int off = s * 32 + quad * 8 + (j & 1) * 4;
        pf[j] = *(const float4*)(Arow + off);
    }

    // stage W f32->f16 (coalesced, all 256 threads; waits drain A too — fine,
    // the MLP burst happens chip-wide during this phase)
    {
        const float4* Wg = (const float4*)W;
        for (int i = tid; i < K_ * D_ / 4; i += 256) {
            const float4 v = Wg[i];
            const int fi = i * 4;
            const int r = fi / D_;
            const int c = fi - r * D_;
            h16x4 h;
            h[0] = (_Float16)v.x; h[1] = (_Float16)v.y;
            h[2] = (_Float16)v.z; h[3] = (_Float16)v.w;
            *(h16x4*)(&Wh[r * WSTRIDE + c]) = h;
        }
    }
    __syncthreads();

    f32x4 acc0 = {0.f, 0.f, 0.f, 0.f};
    f32x4 acc1 = {0.f, 0.f, 0.f, 0.f};
    const int n1 = (16 + m < K_) ? 16 + m : K_ - 1;
    const int kb = w * 192;

    #pragma unroll
    for (int s = 0; s < 6; ++s) {
        const float4 v0 = pf[2 * s], v1 = pf[2 * s + 1];
        f16x8 a;
        a[0] = (_Float16)v0.x; a[1] = (_Float16)v0.y;
        a[2] = (_Float16)v0.z; a[3] = (_Float16)v0.w;
        a[4] = (_Float16)v1.x; a[5] = (_Float16)v1.y;
        a[6] = (_Float16)v1.z; a[7] = (_Float16)v1.w;
        const f16x8 bf = *(const f16x8*)(&Wh[m  * WSTRIDE + kb + s * 32 + quad * 8]);
        const f16x8 cf = *(const f16x8*)(&Wh[n1 * WSTRIDE + kb + s * 32 + quad * 8]);
        acc0 = __builtin_amdgcn_mfma_f32_16x16x32_f16(a, bf, acc0, 0, 0, 0);
        acc1 = __builtin_amdgcn_mfma_f32_16x16x32_f16(a, cf, acc1, 0, 0, 0);
    }

    // cross-wave K reduction: overlay red[4][8][64] f32 (8 KB) on dead Wh
    __syncthreads();                          // all Wh reads done -> safe to overlay
    float* red = reinterpret_cast<float*>(&Wh[0]);
    {
        float* rw = red + (w * 8) * 64 + lane;
        #pragma unroll
        for (int r = 0; r < 4; ++r) {
            rw[r * 64]       = acc0[r];
            rw[(4 + r) * 64] = acc1[r];
        }
    }
    __syncthreads();

    if (w == 0) {
        // epilogue (C layout verified: col=lane&15, row=quad*4+reg)
        const size_t rbase = (size_t)gw * 16 + quad * 4;
        const float bb0 = bias[m];
        #pragma unroll
        for (int r = 0; r < 4; ++r) {
            const float s0 = red[(0 * 8 + r) * 64 + lane] + red[(1 * 8 + r) * 64 + lane]
                           + red[(2 * 8 + r) * 64 + lane] + red[(3 * 8 + r) * 64 + lane];
            out[1 + (rbase + r) * K_ + m] = s0 + bb0;
        }
        const int col2 = 16 + m;
        if (col2 < K_) {
            const float bb1 = bias[col2];
            #pragma unroll
            for (int r = 0; r < 4; ++r) {
                const float s1 = red[(0 * 8 + 4 + r) * 64 + lane] + red[(1 * 8 + 4 + r) * 64 + lane]
                               + red[(2 * 8 + 4 + r) * 64 + lane] + red[(3 * 8 + 4 + r) * 64 + lane];
                out[1 + (rbase + r) * K_ + col2] = s1 + bb1;
            }
        }
    }
}

// ---------------- Kernel 2a: per-(batch,chunk) transfer-matrix product --------
// One wave per task, __launch_bounds__(64,1) gives the full VGPR budget so
// ETc[147] stays in registers (proven config). Arms kernel 2b's counter.
__global__ __launch_bounds__(64, 1) void chunk_kernel(
    const float* __restrict__ outF,
    const int*   __restrict__ mask,
    const float* __restrict__ trans,
    float* __restrict__ G,
    float* __restrict__ SC,
    int*   __restrict__ cnt)
{
    __shared__ float M0[441], M1[441];
    __shared__ float sET[441];
    __shared__ float em[CLEN * K_];
    __shared__ float smx[CLEN];
    __shared__ int   smask[CLEN];

    const int c = blockIdx.x;
    const int b = blockIdx.y;
    const int lane = threadIdx.x;
    if (c == 0 && b == 0 && lane == 0) *cnt = 0;   // arm scan_fin's counter
    const int t0 = c * CLEN + 1;
    const int nst = min(CLEN, T_ - t0);     // 16, except 15 for last chunk
    const int i_ = lane / 3;
    const int jg = lane - i_ * 3;
    const bool act = lane < 63;

    const float* lg = outF + 1 + (size_t)b * T_ * K_;
    for (int idx = lane; idx < nst * K_; idx += 64) em[idx] = lg[t0 * K_ + idx];
    if (lane < nst) smask[lane] = mask[b * T_ + t0 + lane];
    for (int idx = lane; idx < 441; idx += 64) {
        M0[idx] = (idx % 22 == 0) ? 1.0f : 0.0f;
        sET[idx] = __expf(trans[idx]);
    }
    __syncthreads();

    if (lane < nst) {
        float mx = -1e30f;
        for (int j = 0; j < K_; ++j) mx = fmaxf(mx, em[lane * K_ + j]);
        smx[lane] = mx;
    }
    __syncthreads();
    for (int idx = lane; idx < nst * K_; idx += 64)
        em[idx] = __expf(em[idx] - smx[idx / K_]) * (1.0f / 21.0f);

    float ETc[K_ * 7];
    if (act) {
        #pragma unroll
        for (int mm = 0; mm < K_; ++mm) {
            #pragma unroll
            for (int q = 0; q < 7; ++q)
                ETc[mm * 7 + q] = sET[mm * K_ + jg * 7 + q];
        }
    }
    __syncthreads();

    int cur = 0;
    for (int s = 0; s < nst; ++s) {
        if (smask[s] != 0) {                 // wave-uniform
            const float* Mr = cur ? M1 : M0;
            float*       Mw = cur ? M0 : M1;
            float facc[7] = {0.f,0.f,0.f,0.f,0.f,0.f,0.f};
            if (act) {
                #pragma unroll
                for (int mm = 0; mm < K_; ++mm) {
                    const float lm = Mr[i_ * K_ + mm];
                    #pragma unroll
                    for (int q = 0; q < 7; ++q)
                        facc[q] = fmaf(lm, ETc[mm * 7 + q], facc[q]);
                }
            }
            __syncthreads();
            if (act) {
                #pragma unroll
                for (int q = 0; q < 7; ++q)
                    Mw[i_ * K_ + jg * 7 + q] = facc[q] * em[s * K_ + jg * 7 + q];
            }
            __syncthreads();
            cur ^= 1;
        }
    }

    float* Gc = G + (size_t)(b * NCHUNK + c) * GSTRIDE;
    const float* Mf = cur ? M1 : M0;
    for (int idx = lane; idx < 441; idx += 64) Gc[idx] = Mf[idx];
    if (lane == 0) {
        float sc = 0.0f;
        for (int s = 0; s < nst; ++s)
            if (smask[s] != 0) sc += smx[s] + LOG21;
        SC[b * NCHUNK + c] = sc;
    }
}

// ---------------- Kernel 2b: scan + gold score + fused final reduction --------
// 4 waves stage G (56KB) + masks; wave 0 runs the 32-step scan with shuffle-
// broadcast v and lane0-renorm; waves 1-3 compute the gold-path score. Last
// block to arrive (device-scope counter, armed by chunk_kernel) reduces ll/ms
// and writes the loss — no separate fin launch.
__global__ __launch_bounds__(256) void scan_fin_kernel(
    const float* __restrict__ outF,
    const int*   __restrict__ tags,
    const int*   __restrict__ mask,
    const float* __restrict__ trans,
    const float* __restrict__ startT,
    const float* __restrict__ endT,
    const float* __restrict__ G,
    const float* __restrict__ SC,
    float* __restrict__ ll,
    float* __restrict__ msum,
    int*   __restrict__ cnt,
    float* __restrict__ outW)
{
    __shared__ float sG[NCHUNK * GSTRIDE];   // 57344 B
    __shared__ float sm[T_];
    __shared__ int   st[T_];
    __shared__ float part[8];
    __shared__ int   lastF;
    const int tid = threadIdx.x;
    const int lane = tid & 63;
    const int w = tid >> 6;
    const int b = blockIdx.x;
    const float* lg = outF + 1 + (size_t)b * T_ * K_;

    {
        const float4* Gf4 = (const float4*)(G + (size_t)b * NCHUNK * GSTRIDE);
        float4* dst = (float4*)sG;
        for (int i = tid; i < NCHUNK * GSTRIDE / 4; i += 256) dst[i] = Gf4[i];
    }
    for (int t = tid; t < T_; t += 256) {
        sm[t] = (float)mask[b * T_ + t];
        st[t] = tags[b * T_ + t];
    }
    __syncthreads();

    float logZ = 0.0f;
    if (w == 0) {
        const float scv = (lane < NCHUNK) ? SC[b * NCHUNK + lane] : 0.0f;
        const int jc = min(lane, K_ - 1);
        float v = (lane < K_) ? __expf(startT[lane] + lg[lane]) : 0.0f;
        float C = 0.0f;
        for (int c = 0; c < NCHUNK; ++c) {
            const float* Gc = sG + c * GSTRIDE;
            float a0 = 0.f, a1 = 0.f, a2 = 0.f;
            #pragma unroll
            for (int i = 0; i < K_; i += 3) {
                a0 = fmaf(__shfl(v, i,     64), Gc[i * K_ + jc],       a0);
                a1 = fmaf(__shfl(v, i + 1, 64), Gc[(i + 1) * K_ + jc], a1);
                a2 = fmaf(__shfl(v, i + 2, 64), Gc[(i + 2) * K_ + jc], a2);
            }
            const float s = a0 + a1 + a2;
            const float s0 = __shfl(s, 0, 64);     // >0 always (all-positive G)
            v = s / s0;
            C += __logf(s0) + __shfl(scv, c, 64);
        }
        float term = (lane < K_) ? v * __expf(endT[lane]) : 0.0f;
        #pragma unroll
        for (int off = 16; off >= 1; off >>= 1) term += __shfl_xor(term, off, 64);
        term += __shfl_xor(term, 32, 64);
        logZ = C + __logf(term);
    } else {
        float sc = 0.0f, ms = 0.0f;
        for (int t = tid - 64; t < T_; t += 192) {
            const float mt = sm[t];
            ms += mt;
            if (t < T_ - 1) {
                const int ct = st[t], nt2 = st[t + 1];
                sc += trans[ct * K_ + nt2] * sm[t + 1] + lg[t * K_ + ct] * mt;
            }
        }
        #pragma unroll
        for (int off = 32; off >= 1; off >>= 1) {
            sc += __shfl_xor(sc, off, 64);
            ms += __shfl_xor(ms, off, 64);
        }
        if (lane == 0) { part[w] = sc; part[4 + w] = ms; }
    }
    __syncthreads();

    if (tid == 0) {
        float sc = part[1] + part[2] + part[3];
        float ms = part[5] + part[6] + part[7];
        const int lastIdx = (int)ms - 1;
        const int lastTag = st[lastIdx];
        sc += startT[st[0]] + endT[lastTag] + lg[(T_ - 1) * K_ + lastTag] * sm[T_ - 1];
        ll[b]   = sc - logZ;
        msum[b] = ms;
        __threadfence();                          // release our ll/ms
        lastF = (atomicAdd(cnt, 1) == B_ - 1) ? 1 : 0;
    }
    __syncthreads();

    if (lastF != 0 && w == 0) {
        __threadfence();                          // acquire others' ll/ms
        float l  = ll[lane];
        float mm = msum[lane];
        #pragma unroll
        for (int off = 32; off >= 1; off >>= 1) {
            l  += __shfl_xor(l,  off, 64);
            mm += __shfl_xor(mm, off, 64);
        }
        if (lane == 0) outW[0] = -l / mm;
    }
}

// ---------------- Kernel 3 (fallback only): loss = -sum(ll)/sum(mask) ---------
__global__ __launch_bounds__(64) void fin_kernel(
    const float* __restrict__ ll, const float* __restrict__ msum,
    float* __restrict__ outF)
{
    const int lane = threadIdx.x;
    float l = ll[lane];
    float m = msum[lane];
    #pragma unroll
    for (int off = 32; off >= 1; off >>= 1) {
        l += __shfl_xor(l, off, 64);
        m += __shfl_xor(m, off, 64);
    }
    if (lane == 0) outF[0] = -l / m;
}

// ---------------- Fallback (ws too small): sequential CRF ----------------------
__global__ __launch_bounds__(64) void crf_kernel(
    const float* __restrict__ outF,
    const int*   __restrict__ tags,
    const int*   __restrict__ mask,
    const float* __restrict__ trans,
    const float* __restrict__ startT,
    const float* __restrict__ endT,
    float* __restrict__ ws)
{
    __shared__ float se[T_ * K_];
    __shared__ float sm[T_];
    __shared__ int   st[T_];
    const int b = blockIdx.x;
    const int lane = threadIdx.x;

    const float* lg = outF + 1 + (size_t)b * T_ * K_;
    for (int i = lane; i < T_ * K_; i += 64) se[i] = lg[i];
    for (int t = lane; t < T_; t += 64) {
        sm[t] = (float)mask[b * T_ + t];
        st[t] = tags[b * T_ + t];
    }
    __syncthreads();

    const int jc = lane < K_ ? lane : K_ - 1;
    float ET[K_];
    #pragma unroll
    for (int i = 0; i < K_; ++i) ET[i] = __expf(trans[i * K_ + jc]);

    float a0   = startT[jc] + se[jc];
    float r0   = __shfl(a0, 0, 64);
    float aRel = a0 - r0;
    float C    = r0;

    for (int t = 1; t < T_; ++t) {
        if (sm[t] != 0.0f) {
            float e = __expf(aRel);
            float s = 0.0f;
            #pragma unroll
            for (int i = 0; i < K_; ++i)
                s = fmaf(__shfl(e, i, 64), ET[i], s);
            float raw = __logf(s) + se[t * K_ + jc];
            float rr  = __shfl(raw, 0, 64);
            aRel = raw - rr;
            C   += rr;
        }
    }

    float contrib = (lane < K_) ? __expf(aRel + endT[jc]) : 0.0f;
    #pragma unroll
    for (int off = 32; off >= 1; off >>= 1) contrib += __shfl_xor(contrib, off, 64);
    const float logZ = C + __logf(contrib);

    float sc = 0.0f, ms = 0.0f;
    for (int t = lane; t < T_; t += 64) {
        const float mt = sm[t];
        ms += mt;
        if (t < T_ - 1) {
            const int ct = st[t], nt2 = st[t + 1];
            sc += trans[ct * K_ + nt2] * sm[t + 1] + se[t * K_ + ct] * mt;
        }
    }
    #pragma unroll
    for (int off = 32; off >= 1; off >>= 1) {
        sc += __shfl_xor(sc, off, 64);
        ms += __shfl_xor(ms, off, 64);
    }
    if (lane == 0) {
        const int lastIdx = (int)ms - 1;
        const int lastTag = st[lastIdx];
        sc += startT[st[0]] + endT[lastTag] + se[(T_ - 1) * K_ + lastTag] * sm[T_ - 1];
        ws[b]      = sc - logZ;
        ws[B_ + b] = ms;
    }
}

extern "C" void kernel_launch(void* const* d_in, const int* in_sizes, int n_in,
                              void* d_out, int out_size, void* d_ws, size_t ws_size,
                              hipStream_t stream) {
    const float* A     = (const float*)d_in[0];   // vectors [64,512,768] f32
    const int*   tags  = (const int*)  d_in[1];   // targets [64,512] i32
    const int*   mask  = (const int*)  d_in[2];   // mask    [64,512] i32
    const float* W     = (const float*)d_in[3];   // W [21,768] f32
    const float* bias  = (const float*)d_in[4];   // b [21]
    const float* trans = (const float*)d_in[5];   // transitions [21,21]
    const float* stT   = (const float*)d_in[6];   // start_trans [21]
    const float* enT   = (const float*)d_in[7];   // end_trans [21]
    float* outF = (float*)d_out;
    float* ws   = (float*)d_ws;

    // ws layout (floats): G[64*32*448] | SC[64*32] | ll[64] | ms[64] | cnt(int)
    const size_t gFloats = (size_t)B_ * NCHUNK * GSTRIDE;
    const size_t scOff   = gFloats;
    const size_t llOff   = scOff + (size_t)B_ * NCHUNK;
    const size_t msOff   = llOff + B_;
    const size_t cntOff  = msOff + B_;
    const size_t needBytes = cntOff * sizeof(float) + sizeof(int);

    proj_kernel<<<2048, 256, 0, stream>>>(A, W, bias, outF);

    if (ws_size >= needBytes) {
        float* G   = ws;
        float* SC  = ws + scOff;
        float* llp = ws + llOff;
        float* msv = ws + msOff;
        int*   cnt = (int*)(ws + cntOff);
        chunk_kernel<<<dim3(NCHUNK, B_), 64, 0, stream>>>(outF, mask, trans, G, SC, cnt);
        scan_fin_kernel<<<B_, 256, 0, stream>>>(outF, tags, mask, trans, stT, enT, G, SC, llp, msv, cnt, outF);
    } else {
        crf_kernel<<<B_, 64, 0, stream>>>(outF, tags, mask, trans, stT, enT, ws);
        fin_kernel<<<1, 64, 0, stream>>>(ws, ws + B_, outF);
    }
}